// Round 1
// baseline (594.707 us; speedup 1.0000x reference)
//
#include <hip/hip_runtime.h>

#define Nn 8192
#define Ee 262144
#define NEGk 4

// ---- workspace float offsets ----
#define OFF_H1   0u
#define OFF_M1   524288u
#define OFF_V1   1048576u
#define OFF_NN   1572864u
#define OFF_H2   2097152u
#define OFF_V2   2621440u
#define OFF_NV   3145728u
#define OFF_M2   3670016u
#define OFF_SC   4194304u
#define OFF_PR   4202496u
#define OFF_PI   4202624u
#define OFF_PS   4202752u
#define OFF_PH   4202880u
#define OFF_CNT  4203008u
#define OFF_CUR  4211200u
#define OFF_RS   4219392u
#define OFF_ESRC 4227600u
#define OFF_EW   4489744u
#define OFF_EAW  4751888u

__device__ inline float wave_sum(float v){
  #pragma unroll
  for (int o = 32; o > 0; o >>= 1) v += __shfl_down(v, o, 64);
  return v;
}
__device__ inline float wave_max(float v){
  #pragma unroll
  for (int o = 32; o > 0; o >>= 1) v = fmaxf(v, __shfl_down(v, o, 64));
  return v;
}

// ---------------- CSR build ----------------
__global__ __launch_bounds__(256) void zero_k(int* cnt, int* cur){
  int i = blockIdx.x * 256 + threadIdx.x;
  cnt[i] = 0; cur[i] = 0;
}

__global__ __launch_bounds__(256) void hist_k(const int* __restrict__ dst, int* __restrict__ cnt){
  int e = blockIdx.x * 256 + threadIdx.x;
  atomicAdd(&cnt[dst[e]], 1);
}

__global__ __launch_bounds__(256) void scan_k(const int* __restrict__ cnt, int* __restrict__ rs){
  __shared__ int part[256];
  int tid = threadIdx.x;
  int base = tid * 32;
  int local[32]; int s = 0;
  #pragma unroll
  for (int i = 0; i < 32; i++){ local[i] = s; s += cnt[base + i]; }
  part[tid] = s; __syncthreads();
  for (int off = 1; off < 256; off <<= 1){
    int v = (tid >= off) ? part[tid - off] : 0;
    __syncthreads();
    part[tid] += v;
    __syncthreads();
  }
  int ex = part[tid] - s;   // exclusive prefix of this chunk
  #pragma unroll
  for (int i = 0; i < 32; i++) rs[base + i] = ex + local[i];
  if (tid == 255) rs[Nn] = part[255];
}

__global__ __launch_bounds__(256) void scatter_k(const int* __restrict__ dst, const int* __restrict__ src,
    const float* __restrict__ ew, const float* __restrict__ aw,
    const int* __restrict__ rs, int* __restrict__ cur,
    int* __restrict__ cs, float* __restrict__ cw, float* __restrict__ caw){
  int e = blockIdx.x * 256 + threadIdx.x;
  int d = dst[e];
  int pos = atomicAdd(&cur[d], 1);
  int j = rs[d] + pos;
  cs[j] = src[e]; cw[j] = ew[e]; caw[j] = aw[e];
}

// ---------------- small FC: Y = X(Nx64) @ W(64x64) [dual weights / bias+prelu epilogue] ----------------
template<bool DUAL, bool EPI>
__global__ __launch_bounds__(256) void fc_k(const float* __restrict__ X,
    const float* __restrict__ Wa, const float* __restrict__ Wb,
    const float* __restrict__ bias, const float* __restrict__ alpha,
    float* __restrict__ Ya, float* __restrict__ Yb){
  __shared__ float Was[4096];
  __shared__ float Wbs[DUAL ? 4096 : 4];
  __shared__ float As[32 * 65];
  int tid = threadIdx.x;
  for (int i = tid; i < 4096; i += 256) Was[i] = Wa[i];
  if (DUAL) for (int i = tid; i < 4096; i += 256) Wbs[i] = Wb[i];
  int r0 = blockIdx.x * 32;
  for (int i = tid; i < 2048; i += 256){
    int r = i >> 6, c = i & 63;
    As[r * 65 + c] = X[(r0 + r) * 64 + c];
  }
  __syncthreads();
  int tx = tid & 63, wv = tid >> 6;       // each wave owns 8 consecutive rows
  float acca[8], accb[8];
  #pragma unroll
  for (int r = 0; r < 8; r++){ acca[r] = 0.f; accb[r] = 0.f; }
  for (int k = 0; k < 64; k++){
    float wa = Was[k * 64 + tx];
    float wb = DUAL ? Wbs[k * 64 + tx] : 0.f;
    #pragma unroll
    for (int r = 0; r < 8; r++){
      float a = As[(wv * 8 + r) * 65 + k];
      acca[r] += a * wa;
      if (DUAL) accb[r] += a * wb;
    }
  }
  float al = EPI ? alpha[0] : 0.f;
  #pragma unroll
  for (int r = 0; r < 8; r++){
    int row = r0 + wv * 8 + r;
    float x = acca[r];
    if (EPI){ x += bias[tx]; x = (x >= 0.f) ? x : al * x; }
    Ya[row * 64 + tx] = x;
    if (DUAL) Yb[row * 64 + tx] = accb[r];
  }
}

// ---------------- SpMM aggregation (CSR), optional second weight set ----------------
__global__ __launch_bounds__(256) void agg_k(const float* __restrict__ h,
    const int* __restrict__ rs, const int* __restrict__ cs,
    const float* __restrict__ cw, const float* __restrict__ caw,
    const float* __restrict__ bias, const float* __restrict__ alpha,
    float* __restrict__ out1, float* __restrict__ out2){
  int node = (blockIdx.x << 2) + (threadIdx.x >> 6);
  int lane = threadIdx.x & 63;
  int s = rs[node], e = rs[node + 1];
  float acc = 0.f, acc2 = 0.f;
  for (int i = s; i < e; i++){
    int src = cs[i];
    float hv = h[(src << 6) + lane];
    acc += cw[i] * hv;
    if (out2) acc2 += caw[i] * hv;
  }
  float x = acc + bias[lane];
  float al = alpha[0];
  out1[(node << 6) + lane] = (x >= 0.f) ? x : al * x;
  if (out2) out2[(node << 6) + lane] = acc2;
}

// ---------------- per-node dots: p1, p2, score ----------------
__global__ __launch_bounds__(256) void dots_k(const float* __restrict__ nv,
    const float* __restrict__ M1, const float* __restrict__ M2, const float* __restrict__ nn,
    const float* __restrict__ Wsv, const float* __restrict__ bs,
    const float* __restrict__ bd1, const float* __restrict__ bd2,
    float* __restrict__ p1, float* __restrict__ p2, float* __restrict__ score){
  int node = (blockIdx.x << 2) + (threadIdx.x >> 6);
  int t = threadIdx.x & 63;
  float v = nv[(node << 6) + t];
  float s1 = wave_sum(M1[(node << 6) + t] * v);
  float s2 = wave_sum(M2[(node << 6) + t] * nn[(node << 6) + t]);
  float s3 = wave_sum(v * Wsv[t]);
  if (t == 0){
    p1[node] = s1 + bd1[0];
    p2[node] = s2 + bd2[0];
    score[node] = 1.f / (1.f + __expf(-(s3 + bs[0])));
  }
}

// ---------------- negatives: n1[k,n], n2[k,n] ----------------
__global__ __launch_bounds__(256) void neg_k(const float* __restrict__ nv,
    const float* __restrict__ M1, const float* __restrict__ M2, const float* __restrict__ nn,
    const int* __restrict__ neg1, const int* __restrict__ neg2,
    const float* __restrict__ bd1, const float* __restrict__ bd2,
    float* __restrict__ n1, float* __restrict__ n2){
  int gid = (blockIdx.x << 2) + (threadIdx.x >> 6); // 0..NEG*N-1
  int t = threadIdx.x & 63;
  int n = gid & (Nn - 1);
  int i1 = neg1[gid], i2 = neg2[gid];
  float d1 = wave_sum(M1[(i1 << 6) + t] * nv[(n << 6) + t]);
  float d2 = wave_sum(M2[(i2 << 6) + t] * nn[(n << 6) + t]);
  if (t == 0){ n1[gid] = d1 + bd1[0]; n2[gid] = d2 + bd2[0]; }
}

// ---------------- subgraph losses (no sort needed) ----------------
__global__ __launch_bounds__(128) void subg_k(const float* __restrict__ score,
    const int* __restrict__ aidx, const int* __restrict__ nidx,
    const float* __restrict__ alap, const float* __restrict__ nlap,
    float* __restrict__ pr, float* __restrict__ pi, float* __restrict__ ps, float* __restrict__ ph){
  __shared__ float as_[128], ns_[128];
  __shared__ float red[2];
  int s = blockIdx.x, t = threadIdx.x;
  float av = score[aidx[s * 128 + t]];
  float nv = score[nidx[s * 128 + t]];
  as_[t] = av; ns_[t] = nv;
  __syncthreads();
  const float* la = alap + (size_t)s * 16384 + t * 128;
  const float* ln = nlap + (size_t)s * 16384 + t * 128;
  float ya = 0.f, yn = 0.f;
  #pragma unroll 8
  for (int j = 0; j < 128; j += 4){
    float4 wa = *(const float4*)(la + j);
    ya += wa.x * as_[j] + wa.y * as_[j + 1] + wa.z * as_[j + 2] + wa.w * as_[j + 3];
    float4 wn = *(const float4*)(ln + j);
    yn += wn.x * ns_[j] + wn.y * ns_[j + 1] + wn.z * ns_[j + 2] + wn.w * ns_[j + 3];
  }
  float hom = av * ya + nv * yn;
  int wid = t >> 6, lane = t & 63;
  float w;
  w = wave_sum(av);  if (lane == 0) red[wid] = w; __syncthreads();
  float sumA = red[0] + red[1]; __syncthreads();
  w = wave_sum(hom); if (lane == 0) red[wid] = w; __syncthreads();
  float homS = red[0] + red[1]; __syncthreads();
  w = wave_max(av);  if (lane == 0) red[wid] = w; __syncthreads();
  float maxA = fmaxf(red[0], red[1]); __syncthreads();
  w = wave_max(nv);  if (lane == 0) red[wid] = w; __syncthreads();
  float maxN = fmaxf(red[0], red[1]); __syncthreads();
  float mean = sumA * (1.f / 128.f);
  // first-descending-sorted value strictly below mean == max of {x : x < mean}; fallback max
  float below = (av < mean) ? av : -3.0e38f;
  w = wave_max(below); if (lane == 0) red[wid] = w; __syncthreads();
  float mb = fmaxf(red[0], red[1]);
  float a_at_avg = (mb < -1.0e37f) ? maxA : mb;
  if (t == 0){
    pr[s] = fmaxf(0.f, 1.f - maxA + maxN);
    pi[s] = fmaxf(0.f, 1.f - maxA + a_at_avg);
    ps[s] = sumA;
    ph[s] = homS;
  }
}

__global__ __launch_bounds__(128) void fin_k(const float* __restrict__ pr, const float* __restrict__ pi,
    const float* __restrict__ ps, const float* __restrict__ ph, float* __restrict__ out){
  __shared__ float red[2];
  int t = threadIdx.x, wid = t >> 6, lane = t & 63;
  float w;
  w = wave_sum(pr[t]); if (lane == 0) red[wid] = w; __syncthreads();
  float sr = red[0] + red[1]; __syncthreads();
  w = wave_sum(pi[t]); if (lane == 0) red[wid] = w; __syncthreads();
  float si = red[0] + red[1]; __syncthreads();
  w = wave_sum(ps[t]); if (lane == 0) red[wid] = w; __syncthreads();
  float ss = red[0] + red[1]; __syncthreads();
  w = wave_sum(ph[t]); if (lane == 0) red[wid] = w; __syncthreads();
  float sh = red[0] + red[1];
  if (t == 0){
    out[0] = sr * (1.f / 128.f);
    out[1] = si * (1.f / 128.f);
    out[2] = ss * (1.f / 128.f);
    out[3] = sh * (1.f / 256.f);
  }
}

// ---------------- adj_rebuilt = sigmoid(V @ V^T), 128x128 tile / block ----------------
__global__ __launch_bounds__(256) void adj_k(const float* __restrict__ V, float* __restrict__ C){
  __shared__ float As[64 * 128];
  __shared__ float Bs[64 * 128];
  int tid = threadIdx.x;
  int rowBase = blockIdx.y << 7, colBase = blockIdx.x << 7;
  // Stage A transposed: As[k][i] = V[rowBase+i][k]
  for (int i = tid; i < 2048; i += 256){
    int r = i >> 4, kq = (i & 15) << 2;
    float4 v = *(const float4*)(V + ((rowBase + r) << 6) + kq);
    As[(kq    ) * 128 + r] = v.x;
    As[(kq + 1) * 128 + r] = v.y;
    As[(kq + 2) * 128 + r] = v.z;
    As[(kq + 3) * 128 + r] = v.w;
  }
  // Stage B transposed + swizzled: col (tx + 16*cc) stored at [tx*8 + cc] for vector reads
  for (int i = tid; i < 2048; i += 256){
    int c = i >> 4, kq = (i & 15) << 2;
    float4 v = *(const float4*)(V + ((colBase + c) << 6) + kq);
    int sw = ((c & 15) << 3) | (c >> 4);
    Bs[(kq    ) * 128 + sw] = v.x;
    Bs[(kq + 1) * 128 + sw] = v.y;
    Bs[(kq + 2) * 128 + sw] = v.z;
    Bs[(kq + 3) * 128 + sw] = v.w;
  }
  __syncthreads();
  int tx = tid & 15, ty = tid >> 4;
  float acc[8][8];
  #pragma unroll
  for (int r = 0; r < 8; r++)
    #pragma unroll
    for (int c = 0; c < 8; c++) acc[r][c] = 0.f;
  const float* ap = As + (ty << 3);
  const float* bp = Bs + (tx << 3);
  #pragma unroll 4
  for (int k = 0; k < 64; k++){
    float4 a0 = *(const float4*)(ap + k * 128);
    float4 a1 = *(const float4*)(ap + k * 128 + 4);
    float4 b0 = *(const float4*)(bp + k * 128);
    float4 b1 = *(const float4*)(bp + k * 128 + 4);
    float a[8] = {a0.x, a0.y, a0.z, a0.w, a1.x, a1.y, a1.z, a1.w};
    float b[8] = {b0.x, b0.y, b0.z, b0.w, b1.x, b1.y, b1.z, b1.w};
    #pragma unroll
    for (int r = 0; r < 8; r++)
      #pragma unroll
      for (int c = 0; c < 8; c++) acc[r][c] += a[r] * b[c];
  }
  #pragma unroll
  for (int r = 0; r < 8; r++){
    size_t row = (size_t)(rowBase + (ty << 3) + r);
    #pragma unroll
    for (int c = 0; c < 8; c++){
      int col = colBase + tx + (c << 4);
      float x = acc[r][c];
      C[row * Nn + col] = 1.f / (1.f + __expf(-x));
    }
  }
}

extern "C" void kernel_launch(void* const* d_in, const int* in_sizes, int n_in,
                              void* d_out, int out_size, void* d_ws, size_t ws_size,
                              hipStream_t stream) {
  const float* feat  = (const float*)d_in[0];
  const int*   esrc  = (const int*)d_in[1];
  const int*   edst  = (const int*)d_in[2];
  const float* ewv   = (const float*)d_in[3];
  const float* eawv  = (const float*)d_in[4];
  const int*   neg1  = (const int*)d_in[5];
  const int*   neg2  = (const int*)d_in[6];
  const int*   aidx  = (const int*)d_in[7];
  const int*   nidx  = (const int*)d_in[8];
  const float* alap  = (const float*)d_in[9];
  const float* nlap  = (const float*)d_in[10];
  const float* W1    = (const float*)d_in[11];
  const float* b1    = (const float*)d_in[12];
  const float* W2    = (const float*)d_in[13];
  const float* b2    = (const float*)d_in[14];
  const float* Wq    = (const float*)d_in[15];
  const float* bq    = (const float*)d_in[16];
  const float* Wsv   = (const float*)d_in[17];
  const float* bs    = (const float*)d_in[18];
  const float* B1    = (const float*)d_in[19];
  const float* bd1   = (const float*)d_in[20];
  const float* B2    = (const float*)d_in[21];
  const float* bd2   = (const float*)d_in[22];
  const float* a1    = (const float*)d_in[23];
  const float* a2    = (const float*)d_in[24];
  const float* aq    = (const float*)d_in[25];

  float* ws  = (float*)d_ws;
  float* h1  = ws + OFF_H1;
  float* M1  = ws + OFF_M1;
  float* v1  = ws + OFF_V1;
  float* nn  = ws + OFF_NN;
  float* h2  = ws + OFF_H2;
  float* v2  = ws + OFF_V2;
  float* nv  = ws + OFF_NV;
  float* M2  = ws + OFF_M2;
  float* sc  = ws + OFF_SC;
  float* pr  = ws + OFF_PR;
  float* pi  = ws + OFF_PI;
  float* ps  = ws + OFF_PS;
  float* ph  = ws + OFF_PH;
  int*   cnt = (int*)(ws + OFF_CNT);
  int*   cur = (int*)(ws + OFF_CUR);
  int*   rs  = (int*)(ws + OFF_RS);
  int*   cs  = (int*)(ws + OFF_ESRC);
  float* cw  = ws + OFF_EW;
  float* caw = ws + OFF_EAW;

  float* out = (float*)d_out;
  float* adj = out + 4;
  float* p1  = adj + (size_t)Nn * Nn;
  float* n1o = p1 + Nn;
  float* p2  = n1o + NEGk * Nn;
  float* n2o = p2 + Nn;

  // CSR build
  zero_k<<<Nn / 256, 256, 0, stream>>>(cnt, cur);
  hist_k<<<Ee / 256, 256, 0, stream>>>(edst, cnt);
  scan_k<<<1, 256, 0, stream>>>(cnt, rs);
  scatter_k<<<Ee / 256, 256, 0, stream>>>(edst, esrc, ewv, eawv, rs, cur, cs, cw, caw);

  // GCN pipeline
  fc_k<true,  false><<<Nn / 32, 256, 0, stream>>>(feat, W1, B1, nullptr, nullptr, h1, M1);
  agg_k<<<Nn / 4, 256, 0, stream>>>(h1, rs, cs, cw, caw, b1, a1, v1, nn);
  fc_k<false, false><<<Nn / 32, 256, 0, stream>>>(v1, W2, nullptr, nullptr, nullptr, h2, nullptr);
  agg_k<<<Nn / 4, 256, 0, stream>>>(h2, rs, cs, cw, caw, b2, a2, v2, nullptr);
  fc_k<false, true ><<<Nn / 32, 256, 0, stream>>>(v2, Wq, nullptr, bq, aq, nv, nullptr);
  fc_k<false, false><<<Nn / 32, 256, 0, stream>>>(nv, B2, nullptr, nullptr, nullptr, M2, nullptr);

  // discriminators + scores
  dots_k<<<Nn / 4, 256, 0, stream>>>(nv, M1, M2, nn, Wsv, bs, bd1, bd2, p1, p2, sc);
  neg_k<<<NEGk * Nn / 4, 256, 0, stream>>>(nv, M1, M2, nn, neg1, neg2, bd1, bd2, n1o, n2o);

  // subgraph losses
  subg_k<<<128, 128, 0, stream>>>(sc, aidx, nidx, alap, nlap, pr, pi, ps, ph);
  fin_k<<<1, 128, 0, stream>>>(pr, pi, ps, ph, out);

  // big one
  adj_k<<<dim3(Nn / 128, Nn / 128), 256, 0, stream>>>(nv, adj);
}

// Round 2
// 514.296 us; speedup vs baseline: 1.1564x; 1.1564x over previous
//
#include <hip/hip_runtime.h>

#define Nn 8192
#define Ee 262144
#define NEGk 4

// ---- workspace float offsets ----
#define OFF_H1   0u
#define OFF_M1   524288u
#define OFF_V1   1048576u
#define OFF_NN   1572864u
#define OFF_H2   2097152u
#define OFF_V2   2621440u
#define OFF_NV   3145728u
#define OFF_M2   3670016u
#define OFF_SC   4194304u
#define OFF_PR   4202496u
#define OFF_PI   4202624u
#define OFF_PS   4202752u
#define OFF_PH   4202880u
#define OFF_CNT  4203008u
#define OFF_CUR  4211200u
#define OFF_RS   4219392u
#define OFF_ESRC 4227600u
#define OFF_EW   4489744u
#define OFF_EAW  4751888u
#define OFF_NVH  5014032u   // 8192*64 ushort = 262144 floats
#define OFF_NVL  5276176u
#define OFF_WT   5538320u   // 5 * 4096 floats of transposed weights

using short8 = __attribute__((ext_vector_type(8))) short;
using f32x4  = __attribute__((ext_vector_type(4))) float;

__device__ inline float wave_sum(float v){
  #pragma unroll
  for (int o = 32; o > 0; o >>= 1) v += __shfl_down(v, o, 64);
  return v;
}
__device__ inline float wave_max(float v){
  #pragma unroll
  for (int o = 32; o > 0; o >>= 1) v = fmaxf(v, __shfl_down(v, o, 64));
  return v;
}
__device__ inline unsigned short f2bf(float x){
  unsigned u = __float_as_uint(x);
  unsigned r = (u + 0x7FFFu + ((u >> 16) & 1u)) >> 16;
  return (unsigned short)r;
}
__device__ inline float bf2f(unsigned short h){ return __uint_as_float(((unsigned)h) << 16); }

// ---------------- CSR build ----------------
__global__ __launch_bounds__(256) void zero_k(int* cnt, int* cur){
  int i = blockIdx.x * 256 + threadIdx.x;
  cnt[i] = 0; cur[i] = 0;
}

__global__ __launch_bounds__(256) void hist_k(const int* __restrict__ dst, int* __restrict__ cnt){
  int e = blockIdx.x * 256 + threadIdx.x;
  atomicAdd(&cnt[dst[e]], 1);
}

__global__ __launch_bounds__(256) void scan_k(const int* __restrict__ cnt, int* __restrict__ rs){
  __shared__ int part[256];
  int tid = threadIdx.x;
  int base = tid * 32;
  int local[32]; int s = 0;
  #pragma unroll
  for (int i = 0; i < 32; i++){ local[i] = s; s += cnt[base + i]; }
  part[tid] = s; __syncthreads();
  for (int off = 1; off < 256; off <<= 1){
    int v = (tid >= off) ? part[tid - off] : 0;
    __syncthreads();
    part[tid] += v;
    __syncthreads();
  }
  int ex = part[tid] - s;
  #pragma unroll
  for (int i = 0; i < 32; i++) rs[base + i] = ex + local[i];
  if (tid == 255) rs[Nn] = part[255];
}

__global__ __launch_bounds__(256) void scatter_k(const int* __restrict__ dst, const int* __restrict__ src,
    const float* __restrict__ ew, const float* __restrict__ aw,
    const int* __restrict__ rs, int* __restrict__ cur,
    int* __restrict__ cs, float* __restrict__ cw, float* __restrict__ caw){
  int e = blockIdx.x * 256 + threadIdx.x;
  int d = dst[e];
  int pos = atomicAdd(&cur[d], 1);
  int j = rs[d] + pos;
  cs[j] = src[e]; cw[j] = ew[e]; caw[j] = aw[e];
}

// ---------------- transpose the five 64x64 weights: Wt[m][c][k] = W[m][k][c] ----------------
__global__ __launch_bounds__(256) void wtrans_k(const float* __restrict__ W1, const float* __restrict__ B1,
    const float* __restrict__ W2, const float* __restrict__ Wq, const float* __restrict__ B2,
    float* __restrict__ Wt){
  int idx = blockIdx.x * 256 + threadIdx.x;   // 5*4096
  int m = idx >> 12, rc = idx & 4095;
  int k = rc >> 6, c = rc & 63;
  const float* src = (m == 0) ? W1 : (m == 1) ? B1 : (m == 2) ? W2 : (m == 3) ? Wq : B2;
  Wt[m * 4096 + c * 64 + k] = src[k * 64 + c];
}

// ---------------- FC: Y = X(Nx64) @ W(64x64), W pre-transposed; optional dual/epilogue/bf16-split out ----------------
template<bool DUAL, bool EPI, bool BF>
__global__ __launch_bounds__(256) void fc2_k(const float* __restrict__ X,
    const float* __restrict__ WtA, const float* __restrict__ WtB,
    const float* __restrict__ bias, const float* __restrict__ alpha,
    float* __restrict__ Ya, float* __restrict__ Yb,
    unsigned short* __restrict__ hi, unsigned short* __restrict__ lo){
  __shared__ float As[32 * 68];
  int tid = threadIdx.x;
  int r0 = blockIdx.x * 32;
  for (int i = tid; i < 512; i += 256){
    int r = i >> 4, kq = (i & 15) << 2;
    *(float4*)(As + r * 68 + kq) = *(const float4*)(X + (r0 + r) * 64 + kq);
  }
  __syncthreads();
  int tx = tid & 63, wv = tid >> 6;
  float acca[8], accb[8];
  #pragma unroll
  for (int r = 0; r < 8; r++){ acca[r] = 0.f; accb[r] = 0.f; }
  const float* wpa = WtA + tx * 64;
  const float* wpb = DUAL ? (WtB + tx * 64) : WtA;
  #pragma unroll 4
  for (int kq = 0; kq < 64; kq += 4){
    float4 w = *(const float4*)(wpa + kq);
    float4 w2 = *(const float4*)(wpb + kq);
    #pragma unroll
    for (int r = 0; r < 8; r++){
      float4 a = *(const float4*)(As + (wv * 8 + r) * 68 + kq);
      acca[r] += a.x * w.x + a.y * w.y + a.z * w.z + a.w * w.w;
      if (DUAL) accb[r] += a.x * w2.x + a.y * w2.y + a.z * w2.z + a.w * w2.w;
    }
  }
  float al = EPI ? alpha[0] : 0.f;
  float bi = EPI ? bias[tx] : 0.f;
  #pragma unroll
  for (int r = 0; r < 8; r++){
    int row = r0 + wv * 8 + r;
    float x = acca[r];
    if (EPI){ x += bi; x = (x >= 0.f) ? x : al * x; }
    Ya[row * 64 + tx] = x;
    if (BF){
      unsigned short h = f2bf(x);
      hi[row * 64 + tx] = h;
      lo[row * 64 + tx] = f2bf(x - bf2f(h));
    }
    if (DUAL) Yb[row * 64 + tx] = accb[r];
  }
}

// ---------------- SpMM aggregation (CSR), 4x unrolled ----------------
template<bool DUAL>
__global__ __launch_bounds__(256) void agg_k(const float* __restrict__ h,
    const int* __restrict__ rs, const int* __restrict__ cs,
    const float* __restrict__ cw, const float* __restrict__ caw,
    const float* __restrict__ bias, const float* __restrict__ alpha,
    float* __restrict__ out1, float* __restrict__ out2){
  int node = (blockIdx.x << 2) + (threadIdx.x >> 6);
  int lane = threadIdx.x & 63;
  int s = rs[node], e = rs[node + 1];
  float acc = 0.f, acc2 = 0.f;
  int i = s;
  for (; i + 4 <= e; i += 4){
    int s0 = cs[i], s1 = cs[i+1], s2 = cs[i+2], s3 = cs[i+3];
    float w0 = cw[i], w1 = cw[i+1], w2 = cw[i+2], w3 = cw[i+3];
    float h0 = h[(s0 << 6) + lane];
    float h1v = h[(s1 << 6) + lane];
    float h2v = h[(s2 << 6) + lane];
    float h3 = h[(s3 << 6) + lane];
    acc += w0 * h0 + w1 * h1v + w2 * h2v + w3 * h3;
    if (DUAL){
      float a0 = caw[i], a1 = caw[i+1], a2 = caw[i+2], a3 = caw[i+3];
      acc2 += a0 * h0 + a1 * h1v + a2 * h2v + a3 * h3;
    }
  }
  for (; i < e; i++){
    int src = cs[i];
    float hv = h[(src << 6) + lane];
    acc += cw[i] * hv;
    if (DUAL) acc2 += caw[i] * hv;
  }
  float x = acc + bias[lane];
  float al = alpha[0];
  out1[(node << 6) + lane] = (x >= 0.f) ? x : al * x;
  if (DUAL) out2[(node << 6) + lane] = acc2;
}

// ---------------- per-node dots: p1, p2, score ----------------
__global__ __launch_bounds__(256) void dots_k(const float* __restrict__ nv,
    const float* __restrict__ M1, const float* __restrict__ M2, const float* __restrict__ nn,
    const float* __restrict__ Wsv, const float* __restrict__ bs,
    const float* __restrict__ bd1, const float* __restrict__ bd2,
    float* __restrict__ p1, float* __restrict__ p2, float* __restrict__ score){
  int node = (blockIdx.x << 2) + (threadIdx.x >> 6);
  int t = threadIdx.x & 63;
  float v = nv[(node << 6) + t];
  float s1 = wave_sum(M1[(node << 6) + t] * v);
  float s2 = wave_sum(M2[(node << 6) + t] * nn[(node << 6) + t]);
  float s3 = wave_sum(v * Wsv[t]);
  if (t == 0){
    p1[node] = s1 + bd1[0];
    p2[node] = s2 + bd2[0];
    score[node] = 1.f / (1.f + __expf(-(s3 + bs[0])));
  }
}

// ---------------- negatives ----------------
__global__ __launch_bounds__(256) void neg_k(const float* __restrict__ nv,
    const float* __restrict__ M1, const float* __restrict__ M2, const float* __restrict__ nn,
    const int* __restrict__ neg1, const int* __restrict__ neg2,
    const float* __restrict__ bd1, const float* __restrict__ bd2,
    float* __restrict__ n1, float* __restrict__ n2){
  int gid = (blockIdx.x << 2) + (threadIdx.x >> 6);
  int t = threadIdx.x & 63;
  int n = gid & (Nn - 1);
  int i1 = neg1[gid], i2 = neg2[gid];
  float d1 = wave_sum(M1[(i1 << 6) + t] * nv[(n << 6) + t]);
  float d2 = wave_sum(M2[(i2 << 6) + t] * nn[(n << 6) + t]);
  if (t == 0){ n1[gid] = d1 + bd1[0]; n2[gid] = d2 + bd2[0]; }
}

// ---------------- subgraph losses ----------------
__global__ __launch_bounds__(128) void subg_k(const float* __restrict__ score,
    const int* __restrict__ aidx, const int* __restrict__ nidx,
    const float* __restrict__ alap, const float* __restrict__ nlap,
    float* __restrict__ pr, float* __restrict__ pi, float* __restrict__ ps, float* __restrict__ ph){
  __shared__ float as_[128], ns_[128];
  __shared__ float red[2];
  int s = blockIdx.x, t = threadIdx.x;
  float av = score[aidx[s * 128 + t]];
  float nv = score[nidx[s * 128 + t]];
  as_[t] = av; ns_[t] = nv;
  __syncthreads();
  const float* la = alap + (size_t)s * 16384 + t * 128;
  const float* ln = nlap + (size_t)s * 16384 + t * 128;
  float ya = 0.f, yn = 0.f;
  #pragma unroll 8
  for (int j = 0; j < 128; j += 4){
    float4 wa = *(const float4*)(la + j);
    ya += wa.x * as_[j] + wa.y * as_[j + 1] + wa.z * as_[j + 2] + wa.w * as_[j + 3];
    float4 wn = *(const float4*)(ln + j);
    yn += wn.x * ns_[j] + wn.y * ns_[j + 1] + wn.z * ns_[j + 2] + wn.w * ns_[j + 3];
  }
  float hom = av * ya + nv * yn;
  int wid = t >> 6, lane = t & 63;
  float w;
  w = wave_sum(av);  if (lane == 0) red[wid] = w; __syncthreads();
  float sumA = red[0] + red[1]; __syncthreads();
  w = wave_sum(hom); if (lane == 0) red[wid] = w; __syncthreads();
  float homS = red[0] + red[1]; __syncthreads();
  w = wave_max(av);  if (lane == 0) red[wid] = w; __syncthreads();
  float maxA = fmaxf(red[0], red[1]); __syncthreads();
  w = wave_max(nv);  if (lane == 0) red[wid] = w; __syncthreads();
  float maxN = fmaxf(red[0], red[1]); __syncthreads();
  float mean = sumA * (1.f / 128.f);
  float below = (av < mean) ? av : -3.0e38f;
  w = wave_max(below); if (lane == 0) red[wid] = w; __syncthreads();
  float mb = fmaxf(red[0], red[1]);
  float a_at_avg = (mb < -1.0e37f) ? maxA : mb;
  if (t == 0){
    pr[s] = fmaxf(0.f, 1.f - maxA + maxN);
    pi[s] = fmaxf(0.f, 1.f - maxA + a_at_avg);
    ps[s] = sumA;
    ph[s] = homS;
  }
}

__global__ __launch_bounds__(128) void fin_k(const float* __restrict__ pr, const float* __restrict__ pi,
    const float* __restrict__ ps, const float* __restrict__ ph, float* __restrict__ out){
  __shared__ float red[2];
  int t = threadIdx.x, wid = t >> 6, lane = t & 63;
  float w;
  w = wave_sum(pr[t]); if (lane == 0) red[wid] = w; __syncthreads();
  float sr = red[0] + red[1]; __syncthreads();
  w = wave_sum(pi[t]); if (lane == 0) red[wid] = w; __syncthreads();
  float si = red[0] + red[1]; __syncthreads();
  w = wave_sum(ps[t]); if (lane == 0) red[wid] = w; __syncthreads();
  float ss = red[0] + red[1]; __syncthreads();
  w = wave_sum(ph[t]); if (lane == 0) red[wid] = w; __syncthreads();
  float sh = red[0] + red[1];
  if (t == 0){
    out[0] = sr * (1.f / 128.f);
    out[1] = si * (1.f / 128.f);
    out[2] = ss * (1.f / 128.f);
    out[3] = sh * (1.f / 256.f);
  }
}

// ---------------- adj_rebuilt = sigmoid(V @ V^T) via split-bf16 MFMA, no LDS ----------------
// hi/lo bf16 arrays [N,64]; x = hi*hi + hi*lo + lo*hi (drop lo*lo, rel ~2^-18).
// 128x128 tile per block; 4 waves, each a 64x64 quadrant of 4x4 16x16 MFMA tiles.
__global__ __launch_bounds__(256) void adj_mfma_k(const unsigned short* __restrict__ hi,
    const unsigned short* __restrict__ lo, float* __restrict__ C){
  int tid = threadIdx.x;
  int wave = tid >> 6, lane = tid & 63;
  int quad = lane >> 4, m = lane & 15;
  int rowBase = (blockIdx.y << 7) + ((wave >> 1) << 6);
  int colBase = (blockIdx.x << 7) + ((wave & 1) << 6);

  f32x4 acc[4][4];
  #pragma unroll
  for (int i = 0; i < 4; i++)
    #pragma unroll
    for (int j = 0; j < 4; j++) acc[i][j] = (f32x4){0.f, 0.f, 0.f, 0.f};

  // base pointers: lane reads 8 contiguous bf16 at row*64 + khalf*32 + quad*8
  const unsigned short* Ah = hi + ((rowBase + m) << 6) + (quad << 3);
  const unsigned short* Al = lo + ((rowBase + m) << 6) + (quad << 3);
  const unsigned short* Bh = hi + ((colBase + m) << 6) + (quad << 3);
  const unsigned short* Bl = lo + ((colBase + m) << 6) + (quad << 3);

  #pragma unroll
  for (int h = 0; h < 2; h++){
    int ko = h << 5;   // k-half offset in elements
    short8 ah[4], al[4], bh[4], bl[4];
    #pragma unroll
    for (int i = 0; i < 4; i++){
      ah[i] = *(const short8*)(Ah + (i << 10) + ko);
      al[i] = *(const short8*)(Al + (i << 10) + ko);
      bh[i] = *(const short8*)(Bh + (i << 10) + ko);
      bl[i] = *(const short8*)(Bl + (i << 10) + ko);
    }
    #pragma unroll
    for (int i = 0; i < 4; i++)
      #pragma unroll
      for (int j = 0; j < 4; j++){
        acc[i][j] = __builtin_amdgcn_mfma_f32_16x16x32_bf16(ah[i], bh[j], acc[i][j], 0, 0, 0);
        acc[i][j] = __builtin_amdgcn_mfma_f32_16x16x32_bf16(ah[i], bl[j], acc[i][j], 0, 0, 0);
        acc[i][j] = __builtin_amdgcn_mfma_f32_16x16x32_bf16(al[i], bh[j], acc[i][j], 0, 0, 0);
      }
  }

  #pragma unroll
  for (int i = 0; i < 4; i++){
    #pragma unroll
    for (int r = 0; r < 4; r++){
      size_t row = (size_t)(rowBase + (i << 4) + (quad << 2) + r);
      float* cp = C + row * Nn + colBase + m;
      #pragma unroll
      for (int j = 0; j < 4; j++){
        float x = acc[i][j][r];
        cp[j << 4] = 1.f / (1.f + __expf(-x));
      }
    }
  }
}

extern "C" void kernel_launch(void* const* d_in, const int* in_sizes, int n_in,
                              void* d_out, int out_size, void* d_ws, size_t ws_size,
                              hipStream_t stream) {
  const float* feat  = (const float*)d_in[0];
  const int*   esrc  = (const int*)d_in[1];
  const int*   edst  = (const int*)d_in[2];
  const float* ewv   = (const float*)d_in[3];
  const float* eawv  = (const float*)d_in[4];
  const int*   neg1  = (const int*)d_in[5];
  const int*   neg2  = (const int*)d_in[6];
  const int*   aidx  = (const int*)d_in[7];
  const int*   nidx  = (const int*)d_in[8];
  const float* alap  = (const float*)d_in[9];
  const float* nlap  = (const float*)d_in[10];
  const float* W1    = (const float*)d_in[11];
  const float* b1    = (const float*)d_in[12];
  const float* W2    = (const float*)d_in[13];
  const float* b2    = (const float*)d_in[14];
  const float* Wq    = (const float*)d_in[15];
  const float* bq    = (const float*)d_in[16];
  const float* Wsv   = (const float*)d_in[17];
  const float* bs    = (const float*)d_in[18];
  const float* B1    = (const float*)d_in[19];
  const float* bd1   = (const float*)d_in[20];
  const float* B2    = (const float*)d_in[21];
  const float* bd2   = (const float*)d_in[22];
  const float* a1    = (const float*)d_in[23];
  const float* a2    = (const float*)d_in[24];
  const float* aq    = (const float*)d_in[25];

  float* ws  = (float*)d_ws;
  float* h1  = ws + OFF_H1;
  float* M1  = ws + OFF_M1;
  float* v1  = ws + OFF_V1;
  float* nn  = ws + OFF_NN;
  float* h2  = ws + OFF_H2;
  float* v2  = ws + OFF_V2;
  float* nv  = ws + OFF_NV;
  float* M2  = ws + OFF_M2;
  float* sc  = ws + OFF_SC;
  float* pr  = ws + OFF_PR;
  float* pi  = ws + OFF_PI;
  float* ps  = ws + OFF_PS;
  float* ph  = ws + OFF_PH;
  int*   cnt = (int*)(ws + OFF_CNT);
  int*   cur = (int*)(ws + OFF_CUR);
  int*   rs  = (int*)(ws + OFF_RS);
  int*   cs  = (int*)(ws + OFF_ESRC);
  float* cw  = ws + OFF_EW;
  float* caw = ws + OFF_EAW;
  unsigned short* nvh = (unsigned short*)(ws + OFF_NVH);
  unsigned short* nvl = (unsigned short*)(ws + OFF_NVL);
  float* Wt  = ws + OFF_WT;
  float* Wt1 = Wt;           float* WtB1 = Wt + 4096;
  float* Wt2 = Wt + 8192;    float* Wtq  = Wt + 12288;
  float* WtB2 = Wt + 16384;

  float* out = (float*)d_out;
  float* adj = out + 4;
  float* p1  = adj + (size_t)Nn * Nn;
  float* n1o = p1 + Nn;
  float* p2  = n1o + NEGk * Nn;
  float* n2o = p2 + Nn;

  // CSR build + weight transposes
  zero_k<<<Nn / 256, 256, 0, stream>>>(cnt, cur);
  hist_k<<<Ee / 256, 256, 0, stream>>>(edst, cnt);
  wtrans_k<<<80, 256, 0, stream>>>(W1, B1, W2, Wq, B2, Wt);
  scan_k<<<1, 256, 0, stream>>>(cnt, rs);
  scatter_k<<<Ee / 256, 256, 0, stream>>>(edst, esrc, ewv, eawv, rs, cur, cs, cw, caw);

  // GCN pipeline
  fc2_k<true,  false, false><<<Nn / 32, 256, 0, stream>>>(feat, Wt1, WtB1, nullptr, nullptr, h1, M1, nullptr, nullptr);
  agg_k<true ><<<Nn / 4, 256, 0, stream>>>(h1, rs, cs, cw, caw, b1, a1, v1, nn);
  fc2_k<false, false, false><<<Nn / 32, 256, 0, stream>>>(v1, Wt2, nullptr, nullptr, nullptr, h2, nullptr, nullptr, nullptr);
  agg_k<false><<<Nn / 4, 256, 0, stream>>>(h2, rs, cs, cw, caw, b2, a2, v2, nullptr);
  fc2_k<false, true,  true ><<<Nn / 32, 256, 0, stream>>>(v2, Wtq, nullptr, bq, aq, nv, nullptr, nvh, nvl);
  fc2_k<false, false, false><<<Nn / 32, 256, 0, stream>>>(nv, WtB2, nullptr, nullptr, nullptr, M2, nullptr, nullptr, nullptr);

  // discriminators + scores
  dots_k<<<Nn / 4, 256, 0, stream>>>(nv, M1, M2, nn, Wsv, bs, bd1, bd2, p1, p2, sc);
  neg_k<<<NEGk * Nn / 4, 256, 0, stream>>>(nv, M1, M2, nn, neg1, neg2, bd1, bd2, n1o, n2o);

  // subgraph losses
  subg_k<<<128, 128, 0, stream>>>(sc, aidx, nidx, alap, nlap, pr, pi, ps, ph);
  fin_k<<<1, 128, 0, stream>>>(pr, pi, ps, ph, out);

  // big one: split-bf16 MFMA, write-bandwidth-bound
  adj_mfma_k<<<dim3(Nn / 128, Nn / 128), 256, 0, stream>>>(nvh, nvl, adj);
}